// Round 9
// baseline (95.402 us; speedup 1.0000x reference)
//
#include <hip/hip_runtime.h>
#include <math.h>

// (B,T,N,D) = (16,100,128,3), fp32 in, fp32 scalar out.
constexpr int B = 16, T = 100, N = 128;
constexpr float MIN_DIST  = 0.05f;
constexpr float MIN_DIST2 = MIN_DIST * MIN_DIST;

constexpr int THREADS     = 256;
constexpr int MISC_BLOCKS = 160;              // dispatched first (streaming + waiter)
constexpr int PEN_BLOCKS  = B * T;            // 1600 — one (b,t) slice per block
constexpr int TOTAL_BLOCKS = MISC_BLOCKS + PEN_BLOCKS;   // 1760

constexpr int PER_B = T * N * 3;              // 38400 floats per batch
constexpr int PER_T = N * 3;                  // 384 floats per slice

constexpr int WORK_V4_PER_B = (T - 1) * N * 3 / 4;    // 9504
constexpr int WORK_V4 = B * WORK_V4_PER_B;            // 152064
constexpr int KE_V4_PER_SLICE = N * 3 / 4;            // 96
constexpr int KE_V4  = 2 * B * KE_V4_PER_SLICE;       // 3072
constexpr int STAB_V = B * 5 * N;                     // 10240
constexpr int MISC_TOTAL = WORK_V4 + STAB_V + KE_V4;  // 165376

constexpr int WORK_N = B * (T - 1) * N;               // 202752 (mean divisor)

// ws float-index layout (every slot written every call -> no zero-init node):
// [0,1600) pen | [1600,1760) work | [1760,1920) stab | [1920,2080) ke0 | [2080,2240) ke1
// [2304,4064) completion flags (as uint, set to 1u; any initial content != 1u is fine)
constexpr int WORK_OFF = 1600, STAB_OFF = 1760, KE0_OFF = 1920, KE1_OFF = 2080;
constexpr int FLAG_OFF = 2304;

__device__ __forceinline__ float wave_sum(float v) {
#pragma unroll
    for (int off = 32; off > 0; off >>= 1) v += __shfl_down(v, off, 64);
    return v;
}

__global__ __launch_bounds__(THREADS) void physics_one(
    const float* __restrict__ traj, const float* __restrict__ vel,
    const float* __restrict__ frc, float* __restrict__ ws, float* __restrict__ out)
{
    __shared__ float  sraw[PER_T];     // 384 floats raw slice
    __shared__ float4 spos[N];         // 128 padded points
    __shared__ float  red[4][4];
    __shared__ int    pending;

    const int tid  = threadIdx.x;
    const int bid  = blockIdx.x;
    const int lane = tid & 63;
    const int wv   = tid >> 6;
    unsigned* flags = (unsigned*)(ws + FLAG_OFF);

    if (bid >= MISC_BLOCKS) {
        // ---- penetration: one (b,t) slice, unordered pairs once each ----
        const int pb = bid - MISC_BLOCKS;
        if (tid < PER_T / 4)
            ((float4*)sraw)[tid] = ((const float4*)traj)[pb * (PER_T / 4) + tid];
        __syncthreads();
        if (tid < N)
            spos[tid] = make_float4(sraw[3 * tid], sraw[3 * tid + 1], sraw[3 * tid + 2], 0.f);
        __syncthreads();

        // wrap partition: half0 -> k=1..32, half1 -> k=33..63 (+ d=64 diagonal, i<64)
        const int i    = tid & (N - 1);
        const int half = tid >> 7;
        const float4 pi = spos[i];
        float s = 0.f;
        const int klo = 1 + half * 32;
        const int khi = 32 + half * 31;
#pragma unroll 8
        for (int k = klo; k <= khi; ++k) {
            const int j = (i + k) & (N - 1);       // stride-1 across lanes
            const float4 pj = spos[j];
            const float dx = pi.x - pj.x, dy = pi.y - pj.y, dz = pi.z - pj.z;
            const float d2 = dx * dx + dy * dy + dz * dz;
            const bool h = d2 < MIN_DIST2;
            if (__builtin_expect(__any(h), 0))     // hits ~1e-5/pair: coherent skip
                if (h) s += MIN_DIST - sqrtf(d2);
        }
        if (half) {                                // d = 64 diagonal, count once
            const float4 pj = spos[(i + 64) & (N - 1)];
            const float dx = pi.x - pj.x, dy = pi.y - pj.y, dz = pi.z - pj.z;
            const float d2 = dx * dx + dy * dy + dz * dz;
            const bool h = (d2 < MIN_DIST2) & (i < 64);
            if (__builtin_expect(__any(h), 0))
                if (h) s += MIN_DIST - sqrtf(d2);
        }
        float w = wave_sum(s);
        if (lane == 0) red[0][wv] = w;
        __syncthreads();
        if (tid == 0) {
            ws[pb] = red[0][0] + red[0][1] + red[0][2] + red[0][3];
            __threadfence();                       // release partial
            atomicExch(&flags[bid], 1u);           // device-scope flag
        }
        return;
    }

    // ---- misc blocks: work / stability / kinetic, grid-stride ----
    const int mb = bid;
    {
        const float4* t4 = (const float4*)traj;
        const float4* f4 = (const float4*)frc;
        const float4* v4 = (const float4*)vel;
        float sw = 0.f, ss = 0.f, k0 = 0.f, k1 = 0.f;
        const int stride = MISC_BLOCKS * THREADS;
        for (int v = mb * THREADS + tid; v < MISC_TOTAL; v += stride) {
            if (v < WORK_V4) {
                const int b = v / WORK_V4_PER_B;
                const int r = v - b * WORK_V4_PER_B;
                const int base = b * (PER_B / 4) + r;
                const float4 f  = f4[base];
                const float4 t0 = t4[base];
                const float4 t1 = t4[base + PER_T / 4];
                sw += f.x * (t1.x - t0.x) + f.y * (t1.y - t0.y)
                    + f.z * (t1.z - t0.z) + f.w * (t1.w - t0.w);
            } else if (v < WORK_V4 + STAB_V) {
                const int s2 = v - WORK_V4;
                const int b  = s2 / 640;           // 5*N vectors per batch
                const int r  = s2 - b * 640;
                const int e  = b * PER_B + 95 * PER_T + r * 3;
                const float vx = vel[e], vy = vel[e + 1], vz = vel[e + 2];
                ss += sqrtf(vx * vx + vy * vy + vz * vz);
            } else {
                const int s2    = v - WORK_V4 - STAB_V;      // [0,3072)
                const int which = s2 / 1536;                 // 0 -> t=0, 1 -> t=T-1
                const int rr    = s2 - which * 1536;
                const int b     = rr / KE_V4_PER_SLICE;
                const int r     = rr - b * KE_V4_PER_SLICE;
                const float4 q  = v4[b * (PER_B / 4) + which * (99 * PER_T / 4) + r];
                const float k   = q.x * q.x + q.y * q.y + q.z * q.z + q.w * q.w;
                if (which) k1 += k; else k0 += k;
            }
        }
        float vals[4] = {sw, ss, k0, k1};
#pragma unroll
        for (int vv = 0; vv < 4; ++vv) {
            const float w = wave_sum(vals[vv]);
            if (lane == 0) red[vv][wv] = w;
        }
        __syncthreads();
        if (tid == 0) {
            ws[WORK_OFF + mb] = red[0][0] + red[0][1] + red[0][2] + red[0][3];
            ws[STAB_OFF + mb] = red[1][0] + red[1][1] + red[1][2] + red[1][3];
            ws[KE0_OFF  + mb] = red[2][0] + red[2][1] + red[2][2] + red[2][3];
            ws[KE1_OFF  + mb] = red[3][0] + red[3][1] + red[3][2] + red[3][3];
            __threadfence();                       // release partials
            atomicExch(&flags[bid], 1u);           // device-scope flag
        }
    }

    if (bid != 0) return;

    // ---- block 0: wait for all flags (device-scope reads), then finalize ----
    while (true) {
        if (tid == 0) pending = 0;
        __syncthreads();
        int my = 0;
        for (int i2 = tid; i2 < TOTAL_BLOCKS; i2 += THREADS)
            if (atomicOr(&flags[i2], 0u) != 1u) my = 1;
        if (my) pending = 1;                       // benign LDS race
        __syncthreads();
        if (!pending) break;
        __builtin_amdgcn_s_sleep(32);
    }
    __threadfence();                               // acquire partials

    {
        __shared__ float redP[4], redM[4];
        float p = 0.f;
        for (int i2 = tid; i2 < PEN_BLOCKS; i2 += THREADS) p += ws[i2];
        const int base = WORK_OFF + 160 * wv;      // wave wv: work/stab/ke0/ke1
        float m = ws[base + lane] + ws[base + 64 + lane]
                + (lane < 32 ? ws[base + 128 + lane] : 0.f);
        p = wave_sum(p);
        m = wave_sum(m);
        if (lane == 0) { redP[wv] = p; redM[wv] = m; }
        __syncthreads();
        if (tid == 0) {
            const float pen = redP[0] + redP[1] + redP[2] + redP[3];
            const float wk = redM[0], st = redM[1], k0 = redM[2], k1 = redM[3];
            const float pen_loss  = pen / (float)((long long)B * T * (N * (N - 1) / 2));
            const float stab_loss = st / (float)STAB_V;
            const float ke_s = 0.5f * k0 / (float)(B * N);
            const float ke_e = 0.5f * k1 / (float)(B * N);
            const float work = wk / (float)WORK_N;
            out[0] = 10.0f * pen_loss + stab_loss + 0.1f * fabsf(ke_e - ke_s - work);
        }
    }
}

extern "C" void kernel_launch(void* const* d_in, const int* in_sizes, int n_in,
                              void* d_out, int out_size, void* d_ws, size_t ws_size,
                              hipStream_t stream) {
    const float* traj = (const float*)d_in[0];
    const float* vel  = (const float*)d_in[1];
    const float* frc  = (const float*)d_in[2];
    float* out = (float*)d_out;
    float* ws  = (float*)d_ws;

    physics_one<<<TOTAL_BLOCKS, THREADS, 0, stream>>>(traj, vel, frc, ws, out);
}

// Round 10
// 67.999 us; speedup vs baseline: 1.4030x; 1.4030x over previous
//
#include <hip/hip_runtime.h>
#include <math.h>

// (B,T,N,D) = (16,100,128,3), fp32 in, fp32 scalar out.
constexpr int B = 16, T = 100, N = 128;
constexpr float MIN_DIST  = 0.05f;
constexpr float MIN_DIST2 = MIN_DIST * MIN_DIST;

constexpr int THREADS      = 256;
constexpr int PEN_BLOCKS   = B * T;               // 1600 — one block per (b,t) slice
constexpr int MISC_BLOCKS  = 160;                 // scheduled FIRST for overlap
constexpr int TOTAL_BLOCKS = PEN_BLOCKS + MISC_BLOCKS;

constexpr int PER_B = T * N * 3;                  // 38400 floats per batch
constexpr int PER_T = N * 3;                      // 384 floats per slice

// misc work decomposition (work term is elementwise over contiguous ranges)
constexpr int WORK_V4_PER_B = (T - 1) * N * 3 / 4;    // 9504 float4 per batch
constexpr int WORK_V4 = B * WORK_V4_PER_B;            // 152064
constexpr int KE_V4_PER_SLICE = N * 3 / 4;            // 96
constexpr int KE_V4  = 2 * B * KE_V4_PER_SLICE;       // 3072
constexpr int STAB_V = B * 5 * N;                     // 10240 norm vectors
constexpr int MISC_TOTAL = WORK_V4 + STAB_V + KE_V4;  // 165376

constexpr int WORK_N = B * (T - 1) * N;           // 202752 (mean divisor)

// ws layout (every slot written every call -> no zero-init node):
constexpr int WORK_OFF = 1600, STAB_OFF = 1760, KE0_OFF = 1920, KE1_OFF = 2080;

__device__ __forceinline__ float wave_sum(float v) {
#pragma unroll
    for (int off = 32; off > 0; off >>= 1) v += __shfl_down(v, off, 64);
    return v;
}

__global__ __launch_bounds__(THREADS) void physics_fused(
    const float* __restrict__ traj, const float* __restrict__ vel,
    const float* __restrict__ frc, float* __restrict__ ws)
{
    __shared__ float4 spos[N];
    __shared__ float  sraw[PER_T];   // 384 floats, coalesced-staged
    __shared__ float  red[4][4];

    const int tid  = threadIdx.x;
    const int bid  = blockIdx.x;
    const int lane = tid & 63;
    const int wv   = tid >> 6;

    if (bid >= MISC_BLOCKS) {
        // ---- penetration: one (b,t) slice, unordered pairs only ----
        const int pb = bid - MISC_BLOCKS;
        // stage: 96 coalesced float4 loads -> LDS raw
        if (tid < PER_T / 4)
            ((float4*)sraw)[tid] = ((const float4*)traj)[pb * (PER_T / 4) + tid];
        __syncthreads();
        // repack to one float4 per point (b128-friendly compute reads)
        if (tid < N)
            spos[tid] = make_float4(sraw[tid * 3], sraw[tid * 3 + 1], sraw[tid * 3 + 2], 0.f);
        __syncthreads();

        // wrap partition: i = tid&127; half0 -> k=1..32, half1 -> k=33..63 (+k=64, i<64)
        const int i    = tid & (N - 1);
        const int half = tid >> 7;
        const float4 pi = spos[i];
        float s = 0.f;
        const int k0 = 1 + half * 32;
        const int k1 = 32 + half * 31;             // half0: 1..32, half1: 33..63
#pragma unroll 8
        for (int k = k0; k <= k1; ++k) {
            const int j = (i + k) & (N - 1);       // stride-1 across lanes
            const float4 pj = spos[j];
            const float dx = pi.x - pj.x, dy = pi.y - pj.y, dz = pi.z - pj.z;
            const float d2 = dx * dx + dy * dy + dz * dz;
            const bool h = d2 < MIN_DIST2;
            if (__builtin_expect(__any(h), 0))     // hits ~1e-5/pair
                if (h) s += MIN_DIST - sqrtf(d2);
        }
        if (half) {                                // k = 64 diagonal, count once
            const float4 pj = spos[(i + 64) & (N - 1)];
            const float dx = pi.x - pj.x, dy = pi.y - pj.y, dz = pi.z - pj.z;
            const float d2 = dx * dx + dy * dy + dz * dz;
            const bool h = (d2 < MIN_DIST2) & (i < 64);
            if (__builtin_expect(__any(h), 0))
                if (h) s += MIN_DIST - sqrtf(d2);
        }
        float w = wave_sum(s);
        if (lane == 0) red[0][wv] = w;
        __syncthreads();
        if (tid == 0)
            ws[pb] = red[0][0] + red[0][1] + red[0][2] + red[0][3];
    } else {
        // ---- work / stability / kinetic: vectorized grid-stride ----
        const int mb = bid;
        const float4* t4 = (const float4*)traj;
        const float4* f4 = (const float4*)frc;
        const float4* v4 = (const float4*)vel;
        float sw = 0.f, ss = 0.f, k0 = 0.f, k1 = 0.f;
        const int stride = MISC_BLOCKS * THREADS;
        for (int v = mb * THREADS + tid; v < MISC_TOTAL; v += stride) {
            if (v < WORK_V4) {
                const int b = v / WORK_V4_PER_B;
                const int r = v - b * WORK_V4_PER_B;
                const int base = b * (PER_B / 4) + r;
                const float4 f  = f4[base];
                const float4 t0 = t4[base];
                const float4 t1 = t4[base + PER_T / 4];
                sw += f.x * (t1.x - t0.x) + f.y * (t1.y - t0.y)
                    + f.z * (t1.z - t0.z) + f.w * (t1.w - t0.w);
            } else if (v < WORK_V4 + STAB_V) {
                const int s2 = v - WORK_V4;
                const int b  = s2 / 640;           // 5*N vectors per batch
                const int r  = s2 - b * 640;
                const int e  = b * PER_B + 95 * PER_T + r * 3;
                const float vx = vel[e], vy = vel[e + 1], vz = vel[e + 2];
                ss += sqrtf(vx * vx + vy * vy + vz * vz);
            } else {
                const int s2    = v - WORK_V4 - STAB_V;      // [0,3072)
                const int which = s2 / 1536;                 // 0 -> t=0, 1 -> t=T-1
                const int rr    = s2 - which * 1536;
                const int b     = rr / KE_V4_PER_SLICE;
                const int r     = rr - b * KE_V4_PER_SLICE;
                const float4 q  = v4[b * (PER_B / 4) + which * (99 * PER_T / 4) + r];
                const float k   = q.x * q.x + q.y * q.y + q.z * q.z + q.w * q.w;
                if (which) k1 += k; else k0 += k;
            }
        }
        float vals[4] = {sw, ss, k0, k1};
#pragma unroll
        for (int vv = 0; vv < 4; ++vv) {
            const float w = wave_sum(vals[vv]);
            if (lane == 0) red[vv][wv] = w;
        }
        __syncthreads();
        if (tid == 0) {
            ws[WORK_OFF + mb] = red[0][0] + red[0][1] + red[0][2] + red[0][3];
            ws[STAB_OFF + mb] = red[1][0] + red[1][1] + red[1][2] + red[1][3];
            ws[KE0_OFF  + mb] = red[2][0] + red[2][1] + red[2][2] + red[2][3];
            ws[KE1_OFF  + mb] = red[3][0] + red[3][1] + red[3][2] + red[3][3];
        }
    }
}

__global__ __launch_bounds__(256) void physics_finalize(
    const float* __restrict__ ws, float* __restrict__ out)
{
    __shared__ float redP[4], redM[4];
    const int tid = threadIdx.x, lane = tid & 63, wv = tid >> 6;

    float p = 0.f;
    for (int i = tid; i < PEN_BLOCKS; i += 256) p += ws[i];

    const int base = WORK_OFF + 160 * wv;   // wave wv: work/stab/ke0/ke1 segment
    float m = ws[base + lane] + ws[base + 64 + lane]
            + (lane < 32 ? ws[base + 128 + lane] : 0.f);

    p = wave_sum(p);
    m = wave_sum(m);
    if (lane == 0) { redP[wv] = p; redM[wv] = m; }
    __syncthreads();

    if (tid == 0) {
        const float pen = redP[0] + redP[1] + redP[2] + redP[3];  // unordered-pair sum
        const float wk = redM[0], st = redM[1], k0 = redM[2], k1 = redM[3];
        const float pen_loss  = pen / (float)((long long)B * T * (N * (N - 1) / 2));
        const float stab_loss = st / (float)STAB_V;
        const float ke_s = 0.5f * k0 / (float)(B * N);
        const float ke_e = 0.5f * k1 / (float)(B * N);
        const float work = wk / (float)WORK_N;
        out[0] = 10.0f * pen_loss + stab_loss + 0.1f * fabsf(ke_e - ke_s - work);
    }
}

extern "C" void kernel_launch(void* const* d_in, const int* in_sizes, int n_in,
                              void* d_out, int out_size, void* d_ws, size_t ws_size,
                              hipStream_t stream) {
    const float* traj = (const float*)d_in[0];
    const float* vel  = (const float*)d_in[1];
    const float* frc  = (const float*)d_in[2];
    float* out = (float*)d_out;
    float* ws  = (float*)d_ws;

    physics_fused<<<TOTAL_BLOCKS, THREADS, 0, stream>>>(traj, vel, frc, ws);
    physics_finalize<<<1, 256, 0, stream>>>(ws, out);
}